// Round 12
// baseline (143.870 us; speedup 1.0000x reference)
//
#include <hip/hip_runtime.h>
#include <hip/hip_bf16.h>
#include <stdint.h>

// GAT: B=4, N=2048, F_IN=F_OUT=256, H=4
#define H 4
#define BB 4
#define NN 2048
#define FIN 256
#define FOUT 256
#define M_TOT (BB*NN)   // 8192
#define LOG2E 1.44269504f

typedef float f32x4 __attribute__((ext_vector_type(4)));
typedef short s16x8 __attribute__((ext_vector_type(8)));
typedef unsigned int u32;

static __device__ __forceinline__ short f2bf(float f) {
    return __builtin_bit_cast(short, __float2bfloat16(f));
}
static __device__ __forceinline__ float bf2f(short u) {
    unsigned x = ((unsigned)(unsigned short)u) << 16;
    return __builtin_bit_cast(float, x);
}

// ---------------- prep (fused): W->WT (bf16), q = W.a, c = b.a ----------------
__global__ __launch_bounds__(256) void k_prep(const float* __restrict__ W, const float* __restrict__ a,
                                              const float* __restrict__ bvec,
                                              short* __restrict__ WT, float* __restrict__ q,
                                              float* __restrict__ c) {
    int bid = blockIdx.x;
    if (bid < 64) {
        __shared__ float lds[64][65];
        int h = bid >> 4, kt = (bid >> 2) & 3, ot = bid & 3;
        int kb = kt * 64, ob = ot * 64;
        int tx = threadIdx.x & 63, ty = threadIdx.x >> 6;
#pragma unroll
        for (int r = 0; r < 16; ++r) {
            int k_l = ty + r * 4;
            lds[tx][k_l] = W[(size_t)(h * FIN + kb + k_l) * FOUT + ob + tx];
        }
        __syncthreads();
#pragma unroll
        for (int r = 0; r < 16; ++r) {
            int o_l = ty + r * 4;
            WT[(size_t)(h * FOUT + ob + o_l) * FIN + kb + tx] = f2bf(lds[o_l][tx]);
        }
    } else if (bid < 320) {
        int wv = ((bid - 64) * 256 + threadIdx.x) >> 6;  // 0..1023
        int lane = threadIdx.x & 63;
        int h = wv >> 8, f = wv & 255;
        float4 w4 = *(const float4*)(W + (size_t)(h * FIN + f) * FOUT + lane * 4);
        float4 a4 = *(const float4*)(a + h * FOUT + lane * 4);
        float d = w4.x * a4.x + w4.y * a4.y + w4.z * a4.z + w4.w * a4.w;
#pragma unroll
        for (int off = 32; off; off >>= 1) d += __shfl_xor(d, off);
        if (lane == 0) q[h * FIN + f] = d;
    } else {
        int h = threadIdx.x >> 6, lane = threadIdx.x & 63;
        float4 b4 = *(const float4*)(bvec + h * FOUT + lane * 4);
        float4 a4 = *(const float4*)(a + h * FOUT + lane * 4);
        float d = b4.x * a4.x + b4.y * a4.y + b4.z * a4.z + b4.w * a4.w;
#pragma unroll
        for (int off = 32; off; off >>= 1) d += __shfl_xor(d, off);
        if (lane == 0) c[h] = d;
    }
}

// ---------------- scores (exact fp32) + X->bf16 conversion (fused) ----------------
__global__ __launch_bounds__(256) void k_s(const float* __restrict__ X, const float* __restrict__ q,
                                           const float* __restrict__ c, float* __restrict__ s,
                                           short* __restrict__ Xbf) {
    int m = blockIdx.x * 4 + (threadIdx.x >> 6);
    int lane = threadIdx.x & 63;
    float4 xv = *(const float4*)(X + (size_t)m * FIN + lane * 4);
    short4 xb;
    xb.x = f2bf(xv.x); xb.y = f2bf(xv.y); xb.z = f2bf(xv.z); xb.w = f2bf(xv.w);
    *(short4*)(Xbf + (size_t)m * FIN + lane * 4) = xb;
#pragma unroll
    for (int h = 0; h < H; ++h) {
        float4 qv = *(const float4*)(q + h * FIN + lane * 4);
        float d = xv.x * qv.x + xv.y * qv.y + xv.z * qv.z + xv.w * qv.w;
#pragma unroll
        for (int off = 32; off; off >>= 1) d += __shfl_xor(d, off);
        if (lane == 0) s[h * M_TOT + m] = d + c[h];
    }
}

// ---------------- bias -> mask bits + per-row masked max (s staged in LDS) ----------------
__global__ __launch_bounds__(256) void k_maskmax(const float* __restrict__ bias, const float* __restrict__ s,
                                                 unsigned* __restrict__ mask, float* __restrict__ mx) {
    __shared__ float sl[8192];   // 32KB
    int tid = threadIdx.x;
    int row0 = blockIdx.x * 4;
    int b = row0 >> 11;
#pragma unroll
    for (int i = 0; i < 8; ++i) {
        int flat = i * 1024 + tid * 4;
        int h = flat >> 11, j = flat & 2047;
        float4 v = *(const float4*)(s + (size_t)h * M_TOT + (size_t)b * NN + j);
        int phys = flat ^ (((flat >> 5) & 7) << 2);
        *(float4*)(sl + phys) = v;
    }
    __syncthreads();

    int w = tid >> 6, lane = tid & 63;
    int row = row0 + w;
    const float* bp = bias + (size_t)row * NN + lane * 32;
    unsigned bits = 0;
#pragma unroll
    for (int k = 0; k < 8; ++k) {
        float4 v = *(const float4*)(bp + k * 4);
        bits |= (v.x > -1.f ? 1u : 0u) << (k * 4 + 0);
        bits |= (v.y > -1.f ? 1u : 0u) << (k * 4 + 1);
        bits |= (v.z > -1.f ? 1u : 0u) << (k * 4 + 2);
        bits |= (v.w > -1.f ? 1u : 0u) << (k * 4 + 3);
    }
    mask[(size_t)row * 64 + lane] = bits;
#pragma unroll
    for (int h = 0; h < H; ++h) {
        float m = -3e38f;
#pragma unroll
        for (int k = 0; k < 8; ++k) {
            int flat = h * 2048 + lane * 32 + k * 4;
            int phys = flat ^ (((flat >> 5) & 7) << 2);
            float4 sv = *(const float4*)(sl + phys);
            m = fmaxf(m, ((bits >> (k * 4 + 0)) & 1u) ? sv.x : -3e38f);
            m = fmaxf(m, ((bits >> (k * 4 + 1)) & 1u) ? sv.y : -3e38f);
            m = fmaxf(m, ((bits >> (k * 4 + 2)) & 1u) ? sv.z : -3e38f);
            m = fmaxf(m, ((bits >> (k * 4 + 3)) & 1u) ? sv.w : -3e38f);
        }
#pragma unroll
        for (int off = 32; off; off >>= 1) m = fmaxf(m, __shfl_xor(m, off));
        if (lane == 0) mx[h * M_TOT + row] = m;
    }
}

// ---------------- tTs = bf16(X@W + b), stored FRAG-MAJOR ----------------
// per (h,b): 32 j64-tiles x 32 frags x 1KB. fid = o16*2 + j32parity.
// within frag: lane l holds A[o = o16*16 + (l&15)][j = j32base + (l>>4)*8 + e].
__global__ __launch_bounds__(256) void k_gemm_t(const short* __restrict__ WT, const short* __restrict__ Xbf,
                                                const float* __restrict__ bvec, short* __restrict__ tTs) {
    __shared__ short ot[64][136];   // bf16 D-tile [64 o][128 m], pad 8
    int h = blockIdx.z;
    int ob = blockIdx.y * 64;
    int mb = blockIdx.x * 128;
    int tid = threadIdx.x;
    int lane = tid & 63, w = tid >> 6;
    int r16 = lane & 15, g = lane >> 4;
    int mw = mb + w * 32;
    f32x4 acc[4][2] = {};
    for (int k = 0; k < FIN; k += 32) {
        s16x8 afr[4], bfr[2];
#pragma unroll
        for (int fa = 0; fa < 4; ++fa)
            afr[fa] = *(const s16x8*)(WT + (size_t)(h * FOUT + ob + fa * 16 + r16) * FIN + k + g * 8);
#pragma unroll
        for (int fb = 0; fb < 2; ++fb)
            bfr[fb] = *(const s16x8*)(Xbf + (size_t)(mw + fb * 16 + r16) * FIN + k + g * 8);
#pragma unroll
        for (int fa = 0; fa < 4; ++fa)
#pragma unroll
            for (int fb = 0; fb < 2; ++fb)
                acc[fa][fb] = __builtin_amdgcn_mfma_f32_16x16x32_bf16(afr[fa], bfr[fb], acc[fa][fb], 0, 0, 0);
    }
#pragma unroll
    for (int fa = 0; fa < 4; ++fa) {
#pragma unroll
        for (int r = 0; r < 4; ++r) {
            int o_l = fa * 16 + g * 4 + r;
            float bv = bvec[h * FOUT + ob + o_l];
#pragma unroll
            for (int fb = 0; fb < 2; ++fb)
                ot[o_l][w * 32 + fb * 16 + r16] = f2bf(acc[fa][fb][r] + bv);
        }
    }
    __syncthreads();
    int bb = mb >> 11, jloc = mb & 2047;
    int jt0 = jloc >> 6;
    size_t slab = (size_t)((h * 4 + bb) * 32) * 16384;
#pragma unroll
    for (int cc = 0; cc < 4; ++cc) {
        int sid = cc * 256 + tid;       // 0..1023
        int frag = sid >> 6;            // 0..15
        int l = sid & 63;
        int f_l = frag >> 2, jt_sel = (frag >> 1) & 1, par = frag & 1;
        int o_l = f_l * 16 + (l & 15);
        int m_l = jt_sel * 64 + par * 32 + (l >> 4) * 8;
        s16x8 v = *(const s16x8*)&ot[o_l][m_l];
        int fid = ((ob >> 4) + f_l) * 2 + par;
        size_t addr = slab + (size_t)(jt0 + jt_sel) * 16384 + fid * 512 + l * 8;
        *(s16x8*)(tTs + addr) = v;
    }
}

// ---------------- barrier-free softmax-PV: all state in registers ----------------
// 256 threads = 4 waves: wq=w&1 (q-half 32), wo=w>>1 (o-half 128). Block = 64q x 256o, one (h,b).
// Each wave: full j loop (64 x j32 steps). P computed per-wave (2x redundancy across o-waves),
// A-frags streamed frag-major L2->VGPR (dbuf). NO LDS, NO barriers in loop.
// Epilogue: one __syncthreads, LDS tile assembly, coalesced OTn[h][m][o] stores.
__global__ __launch_bounds__(256, 2) void k_attn(const short* __restrict__ tTs, const float* __restrict__ s,
                                                 const unsigned* __restrict__ mask, const float* __restrict__ mx,
                                                 short* __restrict__ OTn) {
    __shared__ short outT[64 * 264];   // 33,792 B (epilogue only)

    // T1: bijective XCD swizzle (512 blocks)
    int flat = blockIdx.x + 32 * (blockIdx.y + 4 * blockIdx.z);
    int swz = (flat & 7) * 64 + (flat >> 3);
    int qt = swz & 31, b = (swz >> 5) & 3, h = swz >> 7;
    int ib = qt * 64;

    int tid = threadIdx.x;
    int lane = tid & 63, w = tid >> 6;
    int l15 = lane & 15, g = lane >> 4;
    int wq = w & 1, wo = w >> 1;
    int wo8 = wo * 8;
    size_t gm = (size_t)b * NN;

    const short* slab = tTs + (size_t)((h * 4 + b) * 32) * 16384;
    const float* srow = s + h * M_TOT + gm;

    // per-lane query rows: q0 = qb + l15, q1 = q0 + 16
    int qb = ib + wq * 32;
    int q0 = qb + l15, q1 = q0 + 16;
    float si0 = srow[q0], si1 = srow[q1];
    float mx0 = mx[h * M_TOT + gm + q0];
    float mx1 = mx[h * M_TOT + gm + q1];
    float z0 = si0 + mx0, z1 = si1 + mx1;
    float M0 = fmaxf(z0, 0.2f * z0) * LOG2E;
    float M1 = fmaxf(z1, 0.2f * z1) * LOG2E;
    // aa = max(fma(sj,k1,c1), fma(sj,k2,c2)) = leaky(si+sj)*LOG2E - M
    float c10 = si0 * LOG2E - M0, c20 = 0.2f * si0 * LOG2E - M0;
    float c11 = si1 * LOG2E - M1, c21 = 0.2f * si1 * LOG2E - M1;
    const float k1 = LOG2E, k2 = 0.2f * LOG2E;
    const unsigned* mk0 = mask + (gm + q0) * 64;
    const unsigned* mk1 = mask + (gm + q1) * 64;
    int go8 = g * 8;

    f32x4 acc[8][2] = {};
    float lsum0 = 0.f, lsum1 = 0.f;

    s16x8 acu[8], anx[8];
#pragma unroll
    for (int f = 0; f < 8; ++f)
        acu[f] = *(const s16x8*)(slab + ((wo8 + f) * 2 + 0) * 512 + lane * 8);
    float4 csj0 = *(const float4*)(srow + go8);
    float4 csj1 = *(const float4*)(srow + go8 + 4);
    unsigned cw0 = mk0[0], cw1 = mk1[0];

    for (int t = 0; t < 64; ++t) {
        // prefetch t+1 (A frags + scores + mask words); waits land next iter
        float4 nsj0, nsj1; unsigned nw0, nw1;
        if (t < 63) {
            const short* tp = slab + (size_t)((t + 1) >> 1) * 16384;
            int pr = (t + 1) & 1;
#pragma unroll
            for (int f = 0; f < 8; ++f)
                anx[f] = *(const s16x8*)(tp + ((wo8 + f) * 2 + pr) * 512 + lane * 8);
            nsj0 = *(const float4*)(srow + (t + 1) * 32 + go8);
            nsj1 = *(const float4*)(srow + (t + 1) * 32 + go8 + 4);
            nw0 = mk0[t + 1];
            nw1 = mk1[t + 1];
        }

        // ---- P production (registers only): j = t*32 + go8 + e ----
        float sjv[8] = {csj0.x, csj0.y, csj0.z, csj0.w, csj1.x, csj1.y, csj1.z, csj1.w};
        unsigned b0 = cw0 >> go8, b1 = cw1 >> go8;
        s16x8 pb0, pb1;
#pragma unroll
        for (int e = 0; e < 8; ++e) {
            float sj = sjv[e];
            float u0 = fmaf(sj, k1, c10), v0 = fmaf(sj, k2, c20);
            float a0 = fmaxf(u0, v0);
            a0 = ((b0 >> e) & 1u) ? a0 : -200.f;
            float p0 = __builtin_amdgcn_exp2f(a0);
            lsum0 += p0;
            pb0[e] = f2bf(p0);
            float u1 = fmaf(sj, k1, c11), v1 = fmaf(sj, k2, c21);
            float a1 = fmaxf(u1, v1);
            a1 = ((b1 >> e) & 1u) ? a1 : -200.f;
            float p1 = __builtin_amdgcn_exp2f(a1);
            lsum1 += p1;
            pb1[e] = f2bf(p1);
        }

        // ---- 8 A-frags x 2 P-frags = 16 MFMA (no sync needed) ----
#pragma unroll
        for (int f = 0; f < 8; ++f) {
            acc[f][0] = __builtin_amdgcn_mfma_f32_16x16x32_bf16(acu[f], pb0, acc[f][0], 0, 0, 0);
            acc[f][1] = __builtin_amdgcn_mfma_f32_16x16x32_bf16(acu[f], pb1, acc[f][1], 0, 0, 0);
        }

        if (t < 63) {
#pragma unroll
            for (int f = 0; f < 8; ++f) acu[f] = anx[f];
            csj0 = nsj0; csj1 = nsj1; cw0 = nw0; cw1 = nw1;
        }
    }

    // ---- epilogue: normalize, assemble [64q][256o] tile in LDS, coalesced store ----
    lsum0 += __shfl_xor(lsum0, 16); lsum0 += __shfl_xor(lsum0, 32);
    lsum1 += __shfl_xor(lsum1, 16); lsum1 += __shfl_xor(lsum1, 32);
    float linv0 = 1.f / lsum0, linv1 = 1.f / lsum1;

    // C layout: lane holds q = qb + qf*16 + l15 (col), o = wo*128 + f*16 + g*4 + r (row)
#pragma unroll
    for (int f = 0; f < 8; ++f) {
        int col = wo * 128 + f * 16 + g * 4;
        short4 o0, o1;
        o0.x = f2bf(acc[f][0][0] * linv0); o0.y = f2bf(acc[f][0][1] * linv0);
        o0.z = f2bf(acc[f][0][2] * linv0); o0.w = f2bf(acc[f][0][3] * linv0);
        o1.x = f2bf(acc[f][1][0] * linv1); o1.y = f2bf(acc[f][1][1] * linv1);
        o1.z = f2bf(acc[f][1][2] * linv1); o1.w = f2bf(acc[f][1][3] * linv1);
        *(short4*)(&outT[(wq * 32 + l15) * 264 + col]) = o0;
        *(short4*)(&outT[(wq * 32 + 16 + l15) * 264 + col]) = o1;
    }
    __syncthreads();
    {
        int row = tid >> 2, off = (tid & 3) * 64;
        size_t gdst = ((size_t)h * M_TOT + gm + ib + row) * 256 + off;
        const short* src = &outT[row * 264 + off];
#pragma unroll
        for (int cc = 0; cc < 8; ++cc)
            *(s16x8*)(OTn + gdst + cc * 8) = *(const s16x8*)(src + cc * 8);
    }
}

// ---------------- head mean (streaming, coalesced): out[m][o] = 0.25 * sum_h OTn[h][m][o] ----------------
__global__ __launch_bounds__(256) void k_reduce(const short* __restrict__ OTn, float* __restrict__ out) {
    size_t idx = ((size_t)blockIdx.x * 256 + threadIdx.x) * 8;
    float acc[8] = {};
#pragma unroll
    for (int h = 0; h < H; ++h) {
        s16x8 v = *(const s16x8*)(OTn + (size_t)h * M_TOT * 256 + idx);
#pragma unroll
        for (int e = 0; e < 8; ++e) acc[e] += bf2f(v[e]);
    }
    float4 o0, o1;
    o0.x = acc[0] * 0.25f; o0.y = acc[1] * 0.25f; o0.z = acc[2] * 0.25f; o0.w = acc[3] * 0.25f;
    o1.x = acc[4] * 0.25f; o1.y = acc[5] * 0.25f; o1.z = acc[6] * 0.25f; o1.w = acc[7] * 0.25f;
    *(float4*)(out + idx) = o0;
    *(float4*)(out + idx + 4) = o1;
}

extern "C" void kernel_launch(void* const* d_in, const int* in_sizes, int n_in,
                              void* d_out, int out_size, void* d_ws, size_t ws_size,
                              hipStream_t stream) {
    const float* X    = (const float*)d_in[0];  // [B,N,FIN]
    const float* bias = (const float*)d_in[1];  // [B,N,N]
    const float* W    = (const float*)d_in[2];  // [H,FIN,FOUT]
    const float* a    = (const float*)d_in[3];  // [H,FOUT]
    const float* bvec = (const float*)d_in[4];  // [H,FOUT]
    float* out = (float*)d_out;                 // [B,N,FOUT] f32

    // workspace layout (~40 MB high-water)
    char* ws = (char*)d_ws;
    short*    Xbf  = (short*)ws;                               //  4 MB  [8192][256] bf16
    short*    WT   = (short*)(ws + (4u << 20));                // 512 KB [H][256][256] bf16
    float*    q    = (float*)(ws + (4u << 20) + (768u << 10)); //  4 KB
    float*    c    = q + H * FIN;                              // 16 B
    float*    s    = (float*)(ws + (5u << 20));                // 128 KB [H][8192]
    float*    mxp  = (float*)(ws + (5u << 20) + (256u << 10)); // 128 KB [H][8192] row max
    short*    tTs  = (short*)(ws + (6u << 20));                // 16 MB  frag-major tiles
    short*    OTn  = (short*)(ws + (22u << 20));               // 16 MB  [H][8192][256] bf16
    unsigned* mask = (unsigned*)(ws + (38u << 20));            //  2 MB  [B][N][N/32] bits

    k_prep<<<321, 256, 0, stream>>>(W, a, bvec, WT, q, c);
    k_s<<<2048, 256, 0, stream>>>(X, q, c, s, Xbf);
    k_maskmax<<<2048, 256, 0, stream>>>(bias, s, mask, mxp);
    k_gemm_t<<<dim3(64, 4, 4), 256, 0, stream>>>(WT, Xbf, bvec, tTs);
    k_attn<<<dim3(32, 4, 4), 256, 0, stream>>>(tTs, s, mask, mxp, OTn);
    k_reduce<<<1024, 256, 0, stream>>>(OTn, out);
}